// Round 10
// baseline (470.309 us; speedup 1.0000x reference)
//
#include <hip/hip_runtime.h>
#include <hip/hip_bf16.h>

// Problem constants
#define B_   2
#define S_   2048
#define HD_  2048
#define H_   4
#define DK_  256
#define DV_  512
#define KD_  1024   // H_*DK_
#define VD_  2048   // H_*DV_
#define ND_  6144   // fused N: q(1024) | k(1024) | v(2048) | g(2048)
#define M_   4096   // B_*S_
#define NCHUNK_ 32
#define CHUNK_  64

typedef __attribute__((ext_vector_type(8))) short bf16x8;
typedef __attribute__((ext_vector_type(4))) float f32x4;
typedef __attribute__((ext_vector_type(4))) unsigned short us4;
typedef __attribute__((ext_vector_type(8))) unsigned short us8;

__device__ __forceinline__ unsigned short f2bf(float f) {
    __hip_bfloat16 h = __float2bfloat16(f);
    return *reinterpret_cast<unsigned short*>(&h);
}
__device__ __forceinline__ float bf2f(unsigned short u) {
    unsigned int x = ((unsigned int)u) << 16;
    return *reinterpret_cast<float*>(&x);
}

// ---------------------------------------------------------------------------
// Weight transpose, ALL FIVE weights in one launch. Wt[n][k](bf16)=W[k][n](f32).
// 32x32 tiles; grid(256, 64): x encodes {Wq:0-31, Wk:32-63, Wv:64-127,
// Wg:128-191, Wo:192-255} n-tiles, y = k-tile (K=2048 for all).
// ---------------------------------------------------------------------------
__global__ __launch_bounds__(256) void tr_w_all(const float* __restrict__ Wq,
                                                const float* __restrict__ Wk,
                                                const float* __restrict__ Wv,
                                                const float* __restrict__ Wg,
                                                const float* __restrict__ Wo,
                                                unsigned short* __restrict__ WcatT,
                                                unsigned short* __restrict__ WotT) {
    __shared__ float Ws[32][33];
    const int t = threadIdx.x;
    const int bx = blockIdx.x;
    const float* W; unsigned short* Wt; int N, nt;
    if (bx < 32)       { W = Wq; Wt = WcatT;                        N = 1024; nt = bx; }
    else if (bx < 64)  { W = Wk; Wt = WcatT + 1024 * 2048;          N = 1024; nt = bx - 32; }
    else if (bx < 128) { W = Wv; Wt = WcatT + 2048 * 2048;          N = 2048; nt = bx - 64; }
    else if (bx < 192) { W = Wg; Wt = WcatT + (size_t)4096 * 2048;  N = 2048; nt = bx - 128; }
    else               { W = Wo; Wt = WotT;                         N = 2048; nt = bx - 192; }
    const int n0 = nt * 32, k0 = blockIdx.y * 32;
    const int r = t >> 3, c4 = (t & 7) * 4;
    float4 a = *(const float4*)&W[(size_t)(k0 + r) * N + n0 + c4];
    Ws[r][c4 + 0] = a.x; Ws[r][c4 + 1] = a.y; Ws[r][c4 + 2] = a.z; Ws[r][c4 + 3] = a.w;
    __syncthreads();
    const int nr = t >> 3, kc4 = (t & 7) * 4;
    us4 w;
#pragma unroll
    for (int j = 0; j < 4; ++j) w[j] = f2bf(Ws[kc4 + j][nr]);
    *(us4*)&Wt[(size_t)(n0 + nr) * 2048 + k0 + kc4] = w;
}

// ---------------------------------------------------------------------------
// v transpose: vT[((b*H+h)*512+e)*2048 + s] = qkvg[(b*2048+s)*6144 + 2048 + h*512 + e]
// bf16 in/out, 32x32 tiles. grid(x = 64 e-tiles, y = 128 s-tiles).
// ---------------------------------------------------------------------------
__global__ __launch_bounds__(256) void tr_v(const unsigned short* __restrict__ qkvg,
                                            unsigned short* __restrict__ vT) {
    __shared__ unsigned short Ws[32][36];
    const int t = threadIdx.x;
    const int c0 = blockIdx.x * 32;      // v-col within VD (0..2047)
    const int s0 = blockIdx.y * 32;      // global s (0..4095)
    {
        const int r = t >> 3, c4 = (t & 7) * 4;
        us4 w = *(const us4*)&qkvg[(size_t)(s0 + r) * ND_ + 2048 + c0 + c4];
        *(us4*)&Ws[r][c4] = w;
    }
    __syncthreads();
    const int er = t >> 3, sc4 = (t & 7) * 4;
    const int c = c0 + er;
    const int h = c >> 9, e = c & 511;
    const int b = s0 >> 11, srow = s0 & 2047;
    us4 w;
#pragma unroll
    for (int j = 0; j < 4; ++j) w[j] = Ws[sc4 + j][er];
    *(us4*)&vT[((size_t)(b * H_ + h) * 512 + e) * 2048 + srow + sc4] = w;
}

// ---------------------------------------------------------------------------
// bf16 GEMM: C[M][N] = A[M][K] @ Bt[N][K]^T. A,Bt bf16 row-major (K-contig).
// 128x128 tile, BK=64, register-prefetch pipelining. XOR-swizzled LDS
// (short_off ^= (row&7)*8) both sides -> conflict-free (verified: 0).
// XCD-aware block swizzle (T1): each XCD gets a contiguous grid chunk so
// blocks sharing A/B panels hit the same L2 (FETCH was 3x unique footprint).
// Requires nwg % 8 == 0 (1536 and 512 both qualify).
// ---------------------------------------------------------------------------
__global__ __launch_bounds__(256) void gemm_bt(const unsigned short* __restrict__ A,
                                               const unsigned short* __restrict__ Bt,
                                               float* __restrict__ Cf,
                                               unsigned short* __restrict__ Cb,
                                               int M, int N, int K) {
    __shared__ __align__(16) unsigned short As[128 * 64];
    __shared__ __align__(16) unsigned short Bs[128 * 64];
    const int t = threadIdx.x;
    // XCD swizzle: lin = dispatch order (x fastest); give each XCD a
    // contiguous chunk of the swizzled index space.
    const int nwg = gridDim.x * gridDim.y;
    const int lin = blockIdx.y * gridDim.x + blockIdx.x;
    const int cpx = nwg >> 3;
    const int swz = (lin & 7) * cpx + (lin >> 3);
    const int bx = swz % gridDim.x, by = swz / gridDim.x;
    const int m0 = by * 128, n0 = bx * 128;
    const int wave = t >> 6, lane = t & 63;
    const int quad = lane >> 4, l16 = lane & 15;
    const int wm = (wave >> 1) * 64, wn = (wave & 1) * 64;

    f32x4 acc[4][4] = {};

    int aoff[4], boff[4], soff[4];
#pragma unroll
    for (int p = 0; p < 4; ++p) {
        int q = t + p * 256;
        int row = q >> 3, c = (q & 7) * 8;
        soff[p] = row * 64 + (c ^ ((row & 7) * 8));        // swizzled LDS dest
        aoff[p] = (m0 + row) * K + c;
        boff[p] = (n0 + row) * K + c;
    }

    us8 pa[4], pb[4];
#pragma unroll
    for (int p = 0; p < 4; ++p) {
        pa[p] = *(const us8*)&A[aoff[p]];
        pb[p] = *(const us8*)&Bt[boff[p]];
    }

    for (int k0 = 0; k0 < K; k0 += 64) {
        __syncthreads();
#pragma unroll
        for (int p = 0; p < 4; ++p) {
            *(us8*)&As[soff[p]] = pa[p];
            *(us8*)&Bs[soff[p]] = pb[p];
        }
        __syncthreads();
        if (k0 + 64 < K) {
#pragma unroll
            for (int p = 0; p < 4; ++p) {
                pa[p] = *(const us8*)&A[aoff[p] + k0 + 64];
                pb[p] = *(const us8*)&Bt[boff[p] + k0 + 64];
            }
        }

#pragma unroll
        for (int ks = 0; ks < 2; ++ks) {
            bf16x8 af[4], bfr[4];
#pragma unroll
            for (int i = 0; i < 4; ++i) {
                int r = wm + i * 16 + l16;
                af[i] = *(const bf16x8*)&As[r * 64 + ((ks * 32 + quad * 8) ^ ((r & 7) * 8))];
            }
#pragma unroll
            for (int j = 0; j < 4; ++j) {
                int r = wn + j * 16 + l16;
                bfr[j] = *(const bf16x8*)&Bs[r * 64 + ((ks * 32 + quad * 8) ^ ((r & 7) * 8))];
            }
#pragma unroll
            for (int i = 0; i < 4; ++i)
#pragma unroll
                for (int j = 0; j < 4; ++j)
                    acc[i][j] = __builtin_amdgcn_mfma_f32_16x16x32_bf16(af[i], bfr[j], acc[i][j], 0, 0, 0);
        }
    }

    if (Cb) {
#pragma unroll
        for (int i = 0; i < 4; ++i)
#pragma unroll
            for (int j = 0; j < 4; ++j)
#pragma unroll
                for (int r = 0; r < 4; ++r)
                    Cb[(size_t)(m0 + wm + i * 16 + quad * 4 + r) * N + n0 + wn + j * 16 + l16] = f2bf(acc[i][j][r]);
    } else {
#pragma unroll
        for (int i = 0; i < 4; ++i)
#pragma unroll
            for (int j = 0; j < 4; ++j)
#pragma unroll
                for (int r = 0; r < 4; ++r)
                    Cf[(size_t)(m0 + wm + i * 16 + quad * 4 + r) * N + n0 + wn + j * 16 + l16] = acc[i][j][r];
    }
}

// ---------------------------------------------------------------------------
// T = X @ Wgk1 (fp32, K=2048, N=16), LDS-staged. FUSED: also emits xb = bf16(X)
// during staging (each X element staged exactly once across the grid).
// ---------------------------------------------------------------------------
__global__ __launch_bounds__(256) void gemm_n16(const float* __restrict__ X,
                                                const float* __restrict__ W,
                                                float* __restrict__ T,
                                                unsigned short* __restrict__ xb) {
    __shared__ float Xs[16][129];
    __shared__ float Wsh[128][17];
    const int t = threadIdx.x;
    const int m0 = blockIdx.x * 16;
    const int mm = t >> 4, jj = t & 15;
    float acc = 0.f;
    for (int k0 = 0; k0 < HD_; k0 += 128) {
        __syncthreads();
#pragma unroll
        for (int p = 0; p < 2; ++p) {
            int q = t + p * 256;
            int r = q >> 5, c4 = (q & 31) * 4;
            float4 a = *(const float4*)&X[(size_t)(m0 + r) * HD_ + k0 + c4];
            Xs[r][c4 + 0] = a.x; Xs[r][c4 + 1] = a.y; Xs[r][c4 + 2] = a.z; Xs[r][c4 + 3] = a.w;
            us4 wv; wv.x = f2bf(a.x); wv.y = f2bf(a.y); wv.z = f2bf(a.z); wv.w = f2bf(a.w);
            *(us4*)&xb[(size_t)(m0 + r) * HD_ + k0 + c4] = wv;
        }
#pragma unroll
        for (int p = 0; p < 8; ++p) {
            int q = t + p * 256;
            int r = q >> 4, c = q & 15;
            Wsh[r][c] = W[(size_t)(k0 + r) * 16 + c];
        }
        __syncthreads();
#pragma unroll 16
        for (int kk = 0; kk < 128; ++kk) acc += Xs[mm][kk] * Wsh[kk][jj];
    }
    T[(size_t)(m0 + mm) * 16 + jj] = acc;
}

// ---------------------------------------------------------------------------
// gk = log_sigmoid(T @ Wgk2 + bgk2) / 16.  (massively parallel — kept
// separate from gate_prep: fusing it into the serial loop measured +23us R4.)
// ---------------------------------------------------------------------------
__global__ __launch_bounds__(256) void gk_act(const float* __restrict__ T,
                                              const float* __restrict__ W2,
                                              const float* __restrict__ b2,
                                              float* __restrict__ gk) {
    const int idx = blockIdx.x * 256 + threadIdx.x;
    const int n = idx & 1023;
    const int m = idx >> 10;
    float acc = b2[n];
#pragma unroll
    for (int j = 0; j < 16; ++j) acc += T[m * 16 + j] * W2[j * 1024 + n];
    float ls = (acc < 0.f) ? (acc - log1pf(expf(acc))) : (-log1pf(expf(-acc)));
    gk[idx] = ls * 0.0625f;  // / GATE_NORMALIZER
}

// ---------------------------------------------------------------------------
// Gate prep, t-PARALLEL: 1024 threads = 4 t-groups x 256 d. Each thread owns
// 16 of the 64 cumsum steps (gk cached in 16 VGPRs); LDS partial-sum scan
// supplies the group prefix. kgT transposed through LDS (odd-stride pad).
// ---------------------------------------------------------------------------
__global__ __launch_bounds__(1024) void gate_prep(const unsigned short* __restrict__ qkvg,
                                                  const float* __restrict__ gk,
                                                  unsigned short* __restrict__ qg,
                                                  unsigned short* __restrict__ kg,
                                                  unsigned short* __restrict__ kgT,
                                                  float* __restrict__ glexp) {
    __shared__ unsigned short kgs[64][265];   // odd stride: conflict-free transpose
    __shared__ float psum[4][256];
    const int tid = threadIdx.x;
    const int d = tid & 255;
    const int ts = tid >> 8;                  // t-group 0..3
    const int bhc = blockIdx.x;
    const int chunk = bhc & 31, bh = bhc >> 5;
    const int h = bh & 3, b = bh >> 2;
    const int col = h * 256 + d;
    const size_t row0 = (size_t)b * S_ + chunk * 64 + ts * 16;

    float g16[16];
    float part = 0.f;
#pragma unroll
    for (int i = 0; i < 16; ++i) {
        g16[i] = gk[(row0 + i) * (size_t)KD_ + col];
        part += g16[i];
    }
    psum[ts][d] = part;
    __syncthreads();
    float gc = 0.f;
#pragma unroll
    for (int j = 0; j < 3; ++j) if (j < ts) gc += psum[j][d];

    const float scale = 0.0625f;  // DK^-0.5
#pragma unroll
    for (int i = 0; i < 16; ++i) {
        gc += g16[i];
        size_t r = row0 + i;
        unsigned short qv = qkvg[r * (size_t)ND_ + col];
        unsigned short kv = qkvg[r * (size_t)ND_ + 1024 + col];
        unsigned short kgv = f2bf(bf2f(kv) * expf(-gc));
        qg[r * (size_t)KD_ + col] = f2bf(bf2f(qv) * expf(gc) * scale);
        kg[r * (size_t)KD_ + col] = kgv;
        kgs[ts * 16 + i][d] = kgv;
    }
    if (ts == 3) glexp[((size_t)bh * 32 + chunk) * 256 + d] = expf(gc);
    __syncthreads();

    // kgT[(bh*256+d)*2048 + chunk*64 + t] — transposed write, us8-vectorized.
    const size_t kgTbase = ((size_t)bh * 256) * 2048 + chunk * 64;
#pragma unroll
    for (int p = 0; p < 2; ++p) {
        int q = p * 1024 + tid;
        int dd = q >> 3, t8 = (q & 7) * 8;
        us8 w;
#pragma unroll
        for (int i = 0; i < 8; ++i) w[i] = kgs[t8 + i][dd];
        *(us8*)&kgT[kgTbase + (size_t)dd * 2048 + t8] = w;
    }
}

// ---------------------------------------------------------------------------
// Pass C1: A_s[bhc][t][j] = tril(q_g k_g^T) (64x64, K=256) -> bf16.
// Register-prefetch pipelined. LDS stride 40 shorts (conflict-free).
// ---------------------------------------------------------------------------
__global__ __launch_bounds__(256) void pass_c1(const unsigned short* __restrict__ qg,
                                               const unsigned short* __restrict__ kg,
                                               unsigned short* __restrict__ Asg) {
    __shared__ __align__(16) unsigned short Aq[64 * 40];
    __shared__ __align__(16) unsigned short Bk[64 * 40];
    const int t = threadIdx.x;
    const int bhc = blockIdx.x;
    const int chunk = bhc & 31, bh = bhc >> 5;
    const int h = bh & 3, b = bh >> 2;
    const int s0 = chunk * 64;
    const int wave = t >> 6, lane = t & 63;
    const int quad = lane >> 4, l16 = lane & 15;
    const int srow = t >> 2, scol = (t & 3) * 8;
    const size_t base = (size_t)b * S_ * KD_ + h * DK_ + (size_t)(s0 + srow) * KD_ + scol;

    f32x4 acc[4] = {};
    us8 aq = *(const us8*)&qg[base];
    us8 bk = *(const us8*)&kg[base];

    for (int k0 = 0; k0 < 256; k0 += 32) {
        __syncthreads();
        *(us8*)&Aq[srow * 40 + scol] = aq;
        *(us8*)&Bk[srow * 40 + scol] = bk;
        __syncthreads();
        if (k0 + 32 < 256) {
            aq = *(const us8*)&qg[base + k0 + 32];
            bk = *(const us8*)&kg[base + k0 + 32];
        }
        bf16x8 bfr = *(const bf16x8*)&Bk[(wave * 16 + l16) * 40 + quad * 8];
#pragma unroll
        for (int i = 0; i < 4; ++i) {
            bf16x8 af = *(const bf16x8*)&Aq[(i * 16 + l16) * 40 + quad * 8];
            acc[i] = __builtin_amdgcn_mfma_f32_16x16x32_bf16(af, bfr, acc[i], 0, 0, 0);
        }
    }

    const int j = wave * 16 + l16;
#pragma unroll
    for (int i = 0; i < 4; ++i)
#pragma unroll
        for (int r = 0; r < 4; ++r) {
            int m = i * 16 + quad * 4 + r;
            float val = (j <= m) ? acc[i][r] : 0.f;
            Asg[(size_t)bhc * 4096 + m * 64 + j] = f2bf(val);
        }
}

// ---------------------------------------------------------------------------
// FUSED Pass A+B, 2 blocks/CU: per block = (64-d, 32-e, bh). Serial chunk
// loop: D = v^T kg (MFMA f32), write ENTERING state S (bf16), then
// S = (S + D) * E[chunk,d]. grid(4, 16, 8) = 512 blocks for 8 waves/CU of
// latency hiding. LDS stride 72 (64 data + 8 pad).
// ---------------------------------------------------------------------------
__global__ __launch_bounds__(256) void pass_ab(const unsigned short* __restrict__ kgT,
                                               const unsigned short* __restrict__ vT,
                                               const float* __restrict__ gle,
                                               unsigned short* __restrict__ St) {
    __shared__ __align__(16) unsigned short As[32 * 72];  // [e][t]
    __shared__ __align__(16) unsigned short Bs[64 * 72];  // [d][t]
    const int t = threadIdx.x;
    const int d0 = blockIdx.x * 64;
    const int e0 = blockIdx.y * 32;
    const int bh = blockIdx.z;
    const int wave = t >> 6, lane = t & 63;
    const int quad = lane >> 4, l16 = lane & 15;
    const int wm = (wave >> 1) * 16;   // e-offset within 32
    const int wn = (wave & 1) * 32;    // d-offset within 64
    const int srow = t >> 3, sc8 = (t & 7) * 8;

    const size_t vb  = ((size_t)bh * 512 + e0 + srow) * 2048 + sc8;
    const size_t kb0 = ((size_t)bh * 256 + d0 + srow) * 2048 + sc8;
    const size_t kb1 = ((size_t)bh * 256 + d0 + 32 + srow) * 2048 + sc8;

    f32x4 S[2] = {};

    for (int n = 0; n < NCHUNK_; ++n) {
        __syncthreads();
        *(us8*)&As[srow * 72 + sc8]        = *(const us8*)&vT[vb + n * 64];
        *(us8*)&Bs[srow * 72 + sc8]        = *(const us8*)&kgT[kb0 + n * 64];
        *(us8*)&Bs[(srow + 32) * 72 + sc8] = *(const us8*)&kgT[kb1 + n * 64];
        __syncthreads();

        f32x4 acc[2] = {};
#pragma unroll
        for (int ks = 0; ks < 2; ++ks) {
            bf16x8 af = *(const bf16x8*)&As[(wm + l16) * 72 + ks * 32 + quad * 8];
#pragma unroll
            for (int j = 0; j < 2; ++j) {
                bf16x8 bfr = *(const bf16x8*)&Bs[(wn + j * 16 + l16) * 72 + ks * 32 + quad * 8];
                acc[j] = __builtin_amdgcn_mfma_f32_16x16x32_bf16(af, bfr, acc[j], 0, 0, 0);
            }
        }

        const float E0 = gle[((size_t)bh * 32 + n) * 256 + d0 + wn + l16];
        const float E1 = gle[((size_t)bh * 32 + n) * 256 + d0 + wn + 16 + l16];
        const size_t obase = ((size_t)(bh * 32 + n)) * 512;
#pragma unroll
        for (int j = 0; j < 2; ++j) {
            const float E = j ? E1 : E0;
#pragma unroll
            for (int r = 0; r < 4; ++r) {
                size_t e = e0 + wm + quad * 4 + r;
                size_t d = d0 + wn + j * 16 + l16;
                St[(obase + e) * 256 + d] = f2bf(S[j][r]);
                S[j][r] = (S[j][r] + acc[j][r]) * E;
            }
        }
    }
}

// ---------------------------------------------------------------------------
// Pass C2: o[t][e] = [A_s | q_g][t][:] @ [v ; S^T][:][e]  (K=320), bf16 out.
// v-staging from vT (contiguous rows); LDS stride 40 (conflict-free).
// grid(x=2 e-half, z=256 bhc).
// ---------------------------------------------------------------------------
__global__ __launch_bounds__(256) void pass_c2(const unsigned short* __restrict__ qg,
                                               const unsigned short* __restrict__ vT,
                                               const unsigned short* __restrict__ Asg,
                                               const unsigned short* __restrict__ St,
                                               unsigned short* __restrict__ o) {
    __shared__ __align__(16) unsigned short At[64 * 40];   // [t][k]
    __shared__ __align__(16) unsigned short Bt[256 * 40];  // [e][k]
    const int t = threadIdx.x;
    const int bhc = blockIdx.z;
    const int chunk = bhc & 31, bh = bhc >> 5;
    const int h = bh & 3, b = bh >> 2;
    const int s0 = chunk * 64;
    const int eh = blockIdx.x * 256;
    const int wave = t >> 6, lane = t & 63;
    const int quad = lane >> 4, l16 = lane & 15;
    const int we = wave * 64;

    f32x4 acc[4][4] = {};

    for (int kk0 = 0; kk0 < 10; ++kk0) {
        __syncthreads();
        if (kk0 < 2) {
            {
                int row = t >> 2, c8 = (t & 3) * 8;
                us8 w = *(const us8*)&Asg[(size_t)bhc * 4096 + row * 64 + kk0 * 32 + c8];
                *(us8*)&At[row * 40 + c8] = w;
            }
            const int t0 = kk0 * 32;
#pragma unroll
            for (int p = 0; p < 4; ++p) {
                int q = t + p * 256;
                int row = q >> 2, c8 = (q & 3) * 8;
                us8 w = *(const us8*)&vT[((size_t)bh * 512 + eh + row) * 2048 + s0 + t0 + c8];
                *(us8*)&Bt[row * 40 + c8] = w;
            }
        } else {
            const int d0 = (kk0 - 2) * 32;
            {
                int row = t >> 2, c8 = (t & 3) * 8;
                us8 w = *(const us8*)&qg[((size_t)b * S_ + s0 + row) * KD_ + h * DK_ + d0 + c8];
                *(us8*)&At[row * 40 + c8] = w;
            }
#pragma unroll
            for (int p = 0; p < 4; ++p) {
                int q = t + p * 256;
                int row = q >> 2, c8 = (q & 3) * 8;
                us8 w = *(const us8*)&St[(((size_t)bhc) * 512 + eh + row) * 256 + d0 + c8];
                *(us8*)&Bt[row * 40 + c8] = w;
            }
        }
        __syncthreads();

        bf16x8 af[4], bfr[4];
#pragma unroll
        for (int i = 0; i < 4; ++i)
            af[i] = *(const bf16x8*)&At[(i * 16 + l16) * 40 + quad * 8];
#pragma unroll
        for (int j = 0; j < 4; ++j)
            bfr[j] = *(const bf16x8*)&Bt[(we + j * 16 + l16) * 40 + quad * 8];
#pragma unroll
        for (int i = 0; i < 4; ++i)
#pragma unroll
            for (int j = 0; j < 4; ++j)
                acc[i][j] = __builtin_amdgcn_mfma_f32_16x16x32_bf16(af[i], bfr[j], acc[i][j], 0, 0, 0);
    }

#pragma unroll
    for (int i = 0; i < 4; ++i)
#pragma unroll
        for (int j = 0; j < 4; ++j)
#pragma unroll
            for (int r = 0; r < 4; ++r) {
                int m = i * 16 + quad * 4 + r;
                int e = eh + we + j * 16 + l16;
                o[((size_t)b * S_ + s0 + m) * VD_ + h * DV_ + e] = f2bf(acc[i][j][r]);
            }
}

// ---------------------------------------------------------------------------
// Post: RMS-norm over Dv=512 per (b,s,h) + gated swish; bf16 o in,
// g from fused qkvg cols (offset 4096, stride ND_), bf16 out.
// ---------------------------------------------------------------------------
__global__ __launch_bounds__(256) void postnorm(const unsigned short* __restrict__ o,
                                                const unsigned short* __restrict__ qkvg,
                                                const float* __restrict__ gnw,
                                                unsigned short* __restrict__ obf) {
    const int row = blockIdx.x;
    const int wave = threadIdx.x >> 6;
    const int lane = threadIdx.x & 63;
    const size_t base = (size_t)row * VD_ + wave * 512;
    const size_t gbase = (size_t)row * ND_ + 4096 + wave * 512;
    float x[8];
    float ss = 0.f;
#pragma unroll
    for (int j = 0; j < 8; ++j) {
        x[j] = bf2f(o[base + lane + j * 64]);
        ss += x[j] * x[j];
    }
#pragma unroll
    for (int off = 32; off; off >>= 1) ss += __shfl_xor(ss, off);
    const float inv = 1.0f / sqrtf(ss * (1.0f / 512.0f) + 1e-5f);
#pragma unroll
    for (int j = 0; j < 8; ++j) {
        int e = lane + j * 64;
        float gv = bf2f(qkvg[gbase + e]);
        float sig = 1.0f / (1.0f + expf(-gv));
        obf[base + e] = f2bf(x[j] * inv * gnw[e] * (gv * sig));
    }
}

// ---------------------------------------------------------------------------
extern "C" void kernel_launch(void* const* d_in, const int* in_sizes, int n_in,
                              void* d_out, int out_size, void* d_ws, size_t ws_size,
                              hipStream_t stream) {
    const float* x    = (const float*)d_in[0];
    const float* Wq   = (const float*)d_in[1];
    const float* Wk   = (const float*)d_in[2];
    const float* Wv   = (const float*)d_in[3];
    const float* Wgk1 = (const float*)d_in[4];
    const float* Wgk2 = (const float*)d_in[5];
    const float* bgk2 = (const float*)d_in[6];
    const float* Wg   = (const float*)d_in[7];
    const float* gnw  = (const float*)d_in[8];
    const float* Wo   = (const float*)d_in[9];
    float* out = (float*)d_out;

    float* ws = (float*)d_ws;
    const size_t MF = 1048576;
    typedef unsigned short us;
    // --- long-lived ---
    us* WotT   = (us*)(ws);                      // [2048][2048] bf16   0..2M
    us* qkvg   = (us*)(ws + 2 * MF);             // [4096][6144] bf16   2..15M (12.58M)
    us* qg     = (us*)(ws + 15 * MF);            // [4096][1024] bf16   15..17M
    us* kg     = (us*)(ws + 17 * MF);            // [4096][1024] bf16   17..19M
    us* kgT    = (us*)(ws + 19 * MF);            // [8*256][2048] bf16  19..21M
    us* vT     = (us*)(ws + 21 * MF);            // [8*512][2048] bf16  21..25M
    float* T   = ws + 25 * MF;                   // 65536
    float* gle = T + 65536;                      // 65536
    us* Asg    = (us*)(ws + 25 * MF + 131072);   // 1M shorts
    us* DtSt   = (us*)(ws + 25 * MF + 786432);   // 32M shorts: 25.75..41.75M
    // --- scratch (lifetime-shared) ---
    us* xb     = (us*)(ws + 41 * MF + 786432);   // x bf16 4M (dead after QKVG GEMM)
    float* gkb = ws + 41 * MF + 786432;          // gk fp32 4M (alias xb; after GEMM, dead after gate_prep)
    us* WcatT  = (us*)(ws + 45 * MF + 786432);   // [6144][2048] bf16 6.29M (dead after QKVG GEMM)
    us* o      = (us*)(ws + 45 * MF + 786432);   // o bf16 4M (alias WcatT; written by pass_c2)
    us* obf    = (us*)(ws + 49 * MF + 786432);   // normed o bf16 2M: 49.75..51.75M

    dim3 blk(256);
    // gemm_n16 also emits xb = bf16(x) during staging (conv fused)
    gemm_n16<<<M_ / 16, blk, 0, stream>>>(x, Wgk1, T, xb);
    // all five weight transposes in one launch
    tr_w_all<<<dim3(256, 64), blk, 0, stream>>>(Wq, Wk, Wv, Wg, Wo, WcatT, WotT);

    // fused projection: qkvg = xb @ WcatT^T  (M=4096, N=6144, K=2048)
    gemm_bt<<<dim3(48, 32), blk, 0, stream>>>(xb, WcatT, nullptr, qkvg, M_, ND_, HD_);
    tr_v<<<dim3(64, 128), blk, 0, stream>>>(qkvg, vT);

    gk_act<<<(M_ * KD_) / 256, blk, 0, stream>>>(T, Wgk2, bgk2, gkb);
    gate_prep<<<256, dim3(1024), 0, stream>>>(qkvg, gkb, qg, kg, kgT, gle);

    pass_c1<<<256, blk, 0, stream>>>(qg, kg, Asg);
    pass_ab<<<dim3(4, 16, 8), blk, 0, stream>>>(kgT, vT, gle, DtSt);
    pass_c2<<<dim3(2, 1, 256), blk, 0, stream>>>(qg, vT, Asg, DtSt, o);
    postnorm<<<M_, blk, 0, stream>>>(o, qkvg, gnw, obf);
    gemm_bt<<<dim3(16, 32), blk, 0, stream>>>(obf, WotT, out, nullptr, M_, HD_, VD_);
}

// Round 12
// 432.767 us; speedup vs baseline: 1.0867x; 1.0867x over previous
//
#include <hip/hip_runtime.h>
#include <hip/hip_bf16.h>

// Problem constants
#define B_   2
#define S_   2048
#define HD_  2048
#define H_   4
#define DK_  256
#define DV_  512
#define KD_  1024   // H_*DK_
#define VD_  2048   // H_*DV_
#define ND_  6144   // fused N: q(1024) | k(1024) | v(2048) | g(2048)
#define M_   4096   // B_*S_
#define NCHUNK_ 32
#define CHUNK_  64

typedef __attribute__((ext_vector_type(8))) short bf16x8;
typedef __attribute__((ext_vector_type(4))) float f32x4;
typedef __attribute__((ext_vector_type(4))) unsigned short us4;
typedef __attribute__((ext_vector_type(8))) unsigned short us8;

__device__ __forceinline__ unsigned short f2bf(float f) {
    __hip_bfloat16 h = __float2bfloat16(f);
    return *reinterpret_cast<unsigned short*>(&h);
}
__device__ __forceinline__ float bf2f(unsigned short u) {
    unsigned int x = ((unsigned int)u) << 16;
    return *reinterpret_cast<float*>(&x);
}

// ---------------------------------------------------------------------------
// Weight transpose, ALL FIVE weights in one launch. Wt[n][k](bf16)=W[k][n](f32).
// 32x32 tiles; grid(256, 64): x encodes {Wq:0-31, Wk:32-63, Wv:64-127,
// Wg:128-191, Wo:192-255} n-tiles, y = k-tile (K=2048 for all).
// ---------------------------------------------------------------------------
__global__ __launch_bounds__(256) void tr_w_all(const float* __restrict__ Wq,
                                                const float* __restrict__ Wk,
                                                const float* __restrict__ Wv,
                                                const float* __restrict__ Wg,
                                                const float* __restrict__ Wo,
                                                unsigned short* __restrict__ WcatT,
                                                unsigned short* __restrict__ WotT) {
    __shared__ float Ws[32][33];
    const int t = threadIdx.x;
    const int bx = blockIdx.x;
    const float* W; unsigned short* Wt; int N, nt;
    if (bx < 32)       { W = Wq; Wt = WcatT;                        N = 1024; nt = bx; }
    else if (bx < 64)  { W = Wk; Wt = WcatT + 1024 * 2048;          N = 1024; nt = bx - 32; }
    else if (bx < 128) { W = Wv; Wt = WcatT + 2048 * 2048;          N = 2048; nt = bx - 64; }
    else if (bx < 192) { W = Wg; Wt = WcatT + (size_t)4096 * 2048;  N = 2048; nt = bx - 128; }
    else               { W = Wo; Wt = WotT;                         N = 2048; nt = bx - 192; }
    const int n0 = nt * 32, k0 = blockIdx.y * 32;
    const int r = t >> 3, c4 = (t & 7) * 4;
    float4 a = *(const float4*)&W[(size_t)(k0 + r) * N + n0 + c4];
    Ws[r][c4 + 0] = a.x; Ws[r][c4 + 1] = a.y; Ws[r][c4 + 2] = a.z; Ws[r][c4 + 3] = a.w;
    __syncthreads();
    const int nr = t >> 3, kc4 = (t & 7) * 4;
    us4 w;
#pragma unroll
    for (int j = 0; j < 4; ++j) w[j] = f2bf(Ws[kc4 + j][nr]);
    *(us4*)&Wt[(size_t)(n0 + nr) * 2048 + k0 + kc4] = w;
}

// ---------------------------------------------------------------------------
// v transpose: vT[((b*H+h)*512+e)*2048 + s] = qkvg[(b*2048+s)*6144 + 2048 + h*512 + e]
// bf16 in/out, 32x32 tiles. grid(x = 64 e-tiles, y = 128 s-tiles).
// ---------------------------------------------------------------------------
__global__ __launch_bounds__(256) void tr_v(const unsigned short* __restrict__ qkvg,
                                            unsigned short* __restrict__ vT) {
    __shared__ unsigned short Ws[32][36];
    const int t = threadIdx.x;
    const int c0 = blockIdx.x * 32;      // v-col within VD (0..2047)
    const int s0 = blockIdx.y * 32;      // global s (0..4095)
    {
        const int r = t >> 3, c4 = (t & 7) * 4;
        us4 w = *(const us4*)&qkvg[(size_t)(s0 + r) * ND_ + 2048 + c0 + c4];
        *(us4*)&Ws[r][c4] = w;
    }
    __syncthreads();
    const int er = t >> 3, sc4 = (t & 7) * 4;
    const int c = c0 + er;
    const int h = c >> 9, e = c & 511;
    const int b = s0 >> 11, srow = s0 & 2047;
    us4 w;
#pragma unroll
    for (int j = 0; j < 4; ++j) w[j] = Ws[sc4 + j][er];
    *(us4*)&vT[((size_t)(b * H_ + h) * 512 + e) * 2048 + srow + sc4] = w;
}

// ---------------------------------------------------------------------------
// bf16 GEMM: C[M][N] = A[M][K] @ Bt[N][K]^T. A,Bt bf16 row-major (K-contig).
// 128x128 tile, BK=64, register-prefetch pipelining. XOR-swizzled LDS
// (short_off ^= (row&7)*8) both sides -> conflict-free (verified: 0).
// NO XCD swizzle: R10 measured it 3x's FETCH (each XCD streams all of B);
// default round-robin keeps the per-XCD working set L2-resident.
// ---------------------------------------------------------------------------
__global__ __launch_bounds__(256) void gemm_bt(const unsigned short* __restrict__ A,
                                               const unsigned short* __restrict__ Bt,
                                               float* __restrict__ Cf,
                                               unsigned short* __restrict__ Cb,
                                               int M, int N, int K) {
    __shared__ __align__(16) unsigned short As[128 * 64];
    __shared__ __align__(16) unsigned short Bs[128 * 64];
    const int t = threadIdx.x;
    const int m0 = blockIdx.y * 128, n0 = blockIdx.x * 128;
    const int wave = t >> 6, lane = t & 63;
    const int quad = lane >> 4, l16 = lane & 15;
    const int wm = (wave >> 1) * 64, wn = (wave & 1) * 64;

    f32x4 acc[4][4] = {};

    int aoff[4], boff[4], soff[4];
#pragma unroll
    for (int p = 0; p < 4; ++p) {
        int q = t + p * 256;
        int row = q >> 3, c = (q & 7) * 8;
        soff[p] = row * 64 + (c ^ ((row & 7) * 8));        // swizzled LDS dest
        aoff[p] = (m0 + row) * K + c;
        boff[p] = (n0 + row) * K + c;
    }

    us8 pa[4], pb[4];
#pragma unroll
    for (int p = 0; p < 4; ++p) {
        pa[p] = *(const us8*)&A[aoff[p]];
        pb[p] = *(const us8*)&Bt[boff[p]];
    }

    for (int k0 = 0; k0 < K; k0 += 64) {
        __syncthreads();
#pragma unroll
        for (int p = 0; p < 4; ++p) {
            *(us8*)&As[soff[p]] = pa[p];
            *(us8*)&Bs[soff[p]] = pb[p];
        }
        __syncthreads();
        if (k0 + 64 < K) {
#pragma unroll
            for (int p = 0; p < 4; ++p) {
                pa[p] = *(const us8*)&A[aoff[p] + k0 + 64];
                pb[p] = *(const us8*)&Bt[boff[p] + k0 + 64];
            }
        }

#pragma unroll
        for (int ks = 0; ks < 2; ++ks) {
            bf16x8 af[4], bfr[4];
#pragma unroll
            for (int i = 0; i < 4; ++i) {
                int r = wm + i * 16 + l16;
                af[i] = *(const bf16x8*)&As[r * 64 + ((ks * 32 + quad * 8) ^ ((r & 7) * 8))];
            }
#pragma unroll
            for (int j = 0; j < 4; ++j) {
                int r = wn + j * 16 + l16;
                bfr[j] = *(const bf16x8*)&Bs[r * 64 + ((ks * 32 + quad * 8) ^ ((r & 7) * 8))];
            }
#pragma unroll
            for (int i = 0; i < 4; ++i)
#pragma unroll
                for (int j = 0; j < 4; ++j)
                    acc[i][j] = __builtin_amdgcn_mfma_f32_16x16x32_bf16(af[i], bfr[j], acc[i][j], 0, 0, 0);
        }
    }

    if (Cb) {
#pragma unroll
        for (int i = 0; i < 4; ++i)
#pragma unroll
            for (int j = 0; j < 4; ++j)
#pragma unroll
                for (int r = 0; r < 4; ++r)
                    Cb[(size_t)(m0 + wm + i * 16 + quad * 4 + r) * N + n0 + wn + j * 16 + l16] = f2bf(acc[i][j][r]);
    } else {
#pragma unroll
        for (int i = 0; i < 4; ++i)
#pragma unroll
            for (int j = 0; j < 4; ++j)
#pragma unroll
                for (int r = 0; r < 4; ++r)
                    Cf[(size_t)(m0 + wm + i * 16 + quad * 4 + r) * N + n0 + wn + j * 16 + l16] = acc[i][j][r];
    }
}

// ---------------------------------------------------------------------------
// T = X @ Wgk1 (fp32, K=2048, N=16), LDS-staged. FUSED: also emits xb = bf16(X)
// during staging (each X element staged exactly once across the grid).
// ---------------------------------------------------------------------------
__global__ __launch_bounds__(256) void gemm_n16(const float* __restrict__ X,
                                                const float* __restrict__ W,
                                                float* __restrict__ T,
                                                unsigned short* __restrict__ xb) {
    __shared__ float Xs[16][129];
    __shared__ float Wsh[128][17];
    const int t = threadIdx.x;
    const int m0 = blockIdx.x * 16;
    const int mm = t >> 4, jj = t & 15;
    float acc = 0.f;
    for (int k0 = 0; k0 < HD_; k0 += 128) {
        __syncthreads();
#pragma unroll
        for (int p = 0; p < 2; ++p) {
            int q = t + p * 256;
            int r = q >> 5, c4 = (q & 31) * 4;
            float4 a = *(const float4*)&X[(size_t)(m0 + r) * HD_ + k0 + c4];
            Xs[r][c4 + 0] = a.x; Xs[r][c4 + 1] = a.y; Xs[r][c4 + 2] = a.z; Xs[r][c4 + 3] = a.w;
            us4 wv; wv.x = f2bf(a.x); wv.y = f2bf(a.y); wv.z = f2bf(a.z); wv.w = f2bf(a.w);
            *(us4*)&xb[(size_t)(m0 + r) * HD_ + k0 + c4] = wv;
        }
#pragma unroll
        for (int p = 0; p < 8; ++p) {
            int q = t + p * 256;
            int r = q >> 4, c = q & 15;
            Wsh[r][c] = W[(size_t)(k0 + r) * 16 + c];
        }
        __syncthreads();
#pragma unroll 16
        for (int kk = 0; kk < 128; ++kk) acc += Xs[mm][kk] * Wsh[kk][jj];
    }
    T[(size_t)(m0 + mm) * 16 + jj] = acc;
}

// ---------------------------------------------------------------------------
// Gate prep, t-PARALLEL + FUSED gk: 1024 threads = 4 t-groups x 256 d.
// gk = logsig(T.W2col + b2)/16 computed IN-REGISTER per thread for its 16
// rows (T chunk staged in LDS, W2 column in 16 VGPRs) — eliminates the
// 33MB fp32 gk round-trip and the gk_act launch. (R4's fusion failed in the
// 64-deep SERIAL loop at 4 waves/CU; here the 16 dots are independent at 16
// waves/CU.) LDS partial-sum scan supplies the cumsum group prefix.
// kgT transposed through LDS (odd-stride pad, us8 writes).
// ---------------------------------------------------------------------------
__global__ __launch_bounds__(1024) void gate_prep(const unsigned short* __restrict__ qkvg,
                                                  const float* __restrict__ T,
                                                  const float* __restrict__ W2,
                                                  const float* __restrict__ b2,
                                                  unsigned short* __restrict__ qg,
                                                  unsigned short* __restrict__ kg,
                                                  unsigned short* __restrict__ kgT,
                                                  float* __restrict__ glexp) {
    __shared__ unsigned short kgs[64][265];   // odd stride: conflict-free transpose
    __shared__ float psum[4][256];
    __shared__ float Tt[64][17];
    const int tid = threadIdx.x;
    const int d = tid & 255;
    const int ts = tid >> 8;                  // t-group 0..3
    const int bhc = blockIdx.x;
    const int chunk = bhc & 31, bh = bhc >> 5;
    const int h = bh & 3, b = bh >> 2;
    const int col = h * 256 + d;
    const size_t crow0 = (size_t)b * S_ + chunk * 64;
    const size_t row0 = crow0 + ts * 16;

    {   // stage T rows for this chunk (64 x 16 fp32), one element per thread
        int r = tid >> 4, c = tid & 15;
        Tt[r][c] = T[(crow0 + r) * 16 + c];
    }
    float w2r[16];
#pragma unroll
    for (int j = 0; j < 16; ++j) w2r[j] = W2[j * 1024 + col];
    const float bb = b2[col];
    __syncthreads();

    // gk for this thread's 16 rows, in-register (same accumulation order as
    // the old gk_act kernel -> bit-identical)
    float g16[16];
    float part = 0.f;
#pragma unroll
    for (int i = 0; i < 16; ++i) {
        float acc = bb;
#pragma unroll
        for (int j = 0; j < 16; ++j) acc += Tt[ts * 16 + i][j] * w2r[j];
        float ls = (acc < 0.f) ? (acc - log1pf(expf(acc))) : (-log1pf(expf(-acc)));
        g16[i] = ls * 0.0625f;  // / GATE_NORMALIZER
        part += g16[i];
    }
    psum[ts][d] = part;
    __syncthreads();
    float gc = 0.f;
#pragma unroll
    for (int j = 0; j < 3; ++j) if (j < ts) gc += psum[j][d];

    const float scale = 0.0625f;  // DK^-0.5
#pragma unroll
    for (int i = 0; i < 16; ++i) {
        gc += g16[i];
        size_t r = row0 + i;
        unsigned short qv = qkvg[r * (size_t)ND_ + col];
        unsigned short kv = qkvg[r * (size_t)ND_ + 1024 + col];
        unsigned short kgv = f2bf(bf2f(kv) * expf(-gc));
        qg[r * (size_t)KD_ + col] = f2bf(bf2f(qv) * expf(gc) * scale);
        kg[r * (size_t)KD_ + col] = kgv;
        kgs[ts * 16 + i][d] = kgv;
    }
    if (ts == 3) glexp[((size_t)bh * 32 + chunk) * 256 + d] = expf(gc);
    __syncthreads();

    // kgT[(bh*256+d)*2048 + chunk*64 + t] — transposed write, us8-vectorized.
    const size_t kgTbase = ((size_t)bh * 256) * 2048 + chunk * 64;
#pragma unroll
    for (int p = 0; p < 2; ++p) {
        int q = p * 1024 + tid;
        int dd = q >> 3, t8 = (q & 7) * 8;
        us8 w;
#pragma unroll
        for (int i = 0; i < 8; ++i) w[i] = kgs[t8 + i][dd];
        *(us8*)&kgT[kgTbase + (size_t)dd * 2048 + t8] = w;
    }
}

// ---------------------------------------------------------------------------
// Pass C1: A_s[bhc][t][j] = tril(q_g k_g^T) (64x64, K=256) -> bf16.
// Register-prefetch pipelined. LDS stride 40 shorts (conflict-free).
// ---------------------------------------------------------------------------
__global__ __launch_bounds__(256) void pass_c1(const unsigned short* __restrict__ qg,
                                               const unsigned short* __restrict__ kg,
                                               unsigned short* __restrict__ Asg) {
    __shared__ __align__(16) unsigned short Aq[64 * 40];
    __shared__ __align__(16) unsigned short Bk[64 * 40];
    const int t = threadIdx.x;
    const int bhc = blockIdx.x;
    const int chunk = bhc & 31, bh = bhc >> 5;
    const int h = bh & 3, b = bh >> 2;
    const int s0 = chunk * 64;
    const int wave = t >> 6, lane = t & 63;
    const int quad = lane >> 4, l16 = lane & 15;
    const int srow = t >> 2, scol = (t & 3) * 8;
    const size_t base = (size_t)b * S_ * KD_ + h * DK_ + (size_t)(s0 + srow) * KD_ + scol;

    f32x4 acc[4] = {};
    us8 aq = *(const us8*)&qg[base];
    us8 bk = *(const us8*)&kg[base];

    for (int k0 = 0; k0 < 256; k0 += 32) {
        __syncthreads();
        *(us8*)&Aq[srow * 40 + scol] = aq;
        *(us8*)&Bk[srow * 40 + scol] = bk;
        __syncthreads();
        if (k0 + 32 < 256) {
            aq = *(const us8*)&qg[base + k0 + 32];
            bk = *(const us8*)&kg[base + k0 + 32];
        }
        bf16x8 bfr = *(const bf16x8*)&Bk[(wave * 16 + l16) * 40 + quad * 8];
#pragma unroll
        for (int i = 0; i < 4; ++i) {
            bf16x8 af = *(const bf16x8*)&Aq[(i * 16 + l16) * 40 + quad * 8];
            acc[i] = __builtin_amdgcn_mfma_f32_16x16x32_bf16(af, bfr, acc[i], 0, 0, 0);
        }
    }

    const int j = wave * 16 + l16;
#pragma unroll
    for (int i = 0; i < 4; ++i)
#pragma unroll
        for (int r = 0; r < 4; ++r) {
            int m = i * 16 + quad * 4 + r;
            float val = (j <= m) ? acc[i][r] : 0.f;
            Asg[(size_t)bhc * 4096 + m * 64 + j] = f2bf(val);
        }
}

// ---------------------------------------------------------------------------
// FUSED Pass A+B, 2 blocks/CU: per block = (64-d, 32-e, bh). Serial chunk
// loop: D = v^T kg (MFMA f32), write ENTERING state S (bf16), then
// S = (S + D) * E[chunk,d]. grid(4, 16, 8) = 512 blocks for 8 waves/CU of
// latency hiding. LDS stride 72 (64 data + 8 pad).
// ---------------------------------------------------------------------------
__global__ __launch_bounds__(256) void pass_ab(const unsigned short* __restrict__ kgT,
                                               const unsigned short* __restrict__ vT,
                                               const float* __restrict__ gle,
                                               unsigned short* __restrict__ St) {
    __shared__ __align__(16) unsigned short As[32 * 72];  // [e][t]
    __shared__ __align__(16) unsigned short Bs[64 * 72];  // [d][t]
    const int t = threadIdx.x;
    const int d0 = blockIdx.x * 64;
    const int e0 = blockIdx.y * 32;
    const int bh = blockIdx.z;
    const int wave = t >> 6, lane = t & 63;
    const int quad = lane >> 4, l16 = lane & 15;
    const int wm = (wave >> 1) * 16;   // e-offset within 32
    const int wn = (wave & 1) * 32;    // d-offset within 64
    const int srow = t >> 3, sc8 = (t & 7) * 8;

    const size_t vb  = ((size_t)bh * 512 + e0 + srow) * 2048 + sc8;
    const size_t kb0 = ((size_t)bh * 256 + d0 + srow) * 2048 + sc8;
    const size_t kb1 = ((size_t)bh * 256 + d0 + 32 + srow) * 2048 + sc8;

    f32x4 S[2] = {};

    for (int n = 0; n < NCHUNK_; ++n) {
        __syncthreads();
        *(us8*)&As[srow * 72 + sc8]        = *(const us8*)&vT[vb + n * 64];
        *(us8*)&Bs[srow * 72 + sc8]        = *(const us8*)&kgT[kb0 + n * 64];
        *(us8*)&Bs[(srow + 32) * 72 + sc8] = *(const us8*)&kgT[kb1 + n * 64];
        __syncthreads();

        f32x4 acc[2] = {};
#pragma unroll
        for (int ks = 0; ks < 2; ++ks) {
            bf16x8 af = *(const bf16x8*)&As[(wm + l16) * 72 + ks * 32 + quad * 8];
#pragma unroll
            for (int j = 0; j < 2; ++j) {
                bf16x8 bfr = *(const bf16x8*)&Bs[(wn + j * 16 + l16) * 72 + ks * 32 + quad * 8];
                acc[j] = __builtin_amdgcn_mfma_f32_16x16x32_bf16(af, bfr, acc[j], 0, 0, 0);
            }
        }

        const float E0 = gle[((size_t)bh * 32 + n) * 256 + d0 + wn + l16];
        const float E1 = gle[((size_t)bh * 32 + n) * 256 + d0 + wn + 16 + l16];
        const size_t obase = ((size_t)(bh * 32 + n)) * 512;
#pragma unroll
        for (int j = 0; j < 2; ++j) {
            const float E = j ? E1 : E0;
#pragma unroll
            for (int r = 0; r < 4; ++r) {
                size_t e = e0 + wm + quad * 4 + r;
                size_t d = d0 + wn + j * 16 + l16;
                St[(obase + e) * 256 + d] = f2bf(S[j][r]);
                S[j][r] = (S[j][r] + acc[j][r]) * E;
            }
        }
    }
}

// ---------------------------------------------------------------------------
// Pass C2: o[t][e] = [A_s | q_g][t][:] @ [v ; S^T][:][e]  (K=320), bf16 out.
// v-staging from vT (contiguous rows); LDS stride 40 (conflict-free).
// grid(x=2 e-half, z=256 bhc).
// ---------------------------------------------------------------------------
__global__ __launch_bounds__(256) void pass_c2(const unsigned short* __restrict__ qg,
                                               const unsigned short* __restrict__ vT,
                                               const unsigned short* __restrict__ Asg,
                                               const unsigned short* __restrict__ St,
                                               unsigned short* __restrict__ o) {
    __shared__ __align__(16) unsigned short At[64 * 40];   // [t][k]
    __shared__ __align__(16) unsigned short Bt[256 * 40];  // [e][k]
    const int t = threadIdx.x;
    const int bhc = blockIdx.z;
    const int chunk = bhc & 31, bh = bhc >> 5;
    const int h = bh & 3, b = bh >> 2;
    const int s0 = chunk * 64;
    const int eh = blockIdx.x * 256;
    const int wave = t >> 6, lane = t & 63;
    const int quad = lane >> 4, l16 = lane & 15;
    const int we = wave * 64;

    f32x4 acc[4][4] = {};

    for (int kk0 = 0; kk0 < 10; ++kk0) {
        __syncthreads();
        if (kk0 < 2) {
            {
                int row = t >> 2, c8 = (t & 3) * 8;
                us8 w = *(const us8*)&Asg[(size_t)bhc * 4096 + row * 64 + kk0 * 32 + c8];
                *(us8*)&At[row * 40 + c8] = w;
            }
            const int t0 = kk0 * 32;
#pragma unroll
            for (int p = 0; p < 4; ++p) {
                int q = t + p * 256;
                int row = q >> 2, c8 = (q & 3) * 8;
                us8 w = *(const us8*)&vT[((size_t)bh * 512 + eh + row) * 2048 + s0 + t0 + c8];
                *(us8*)&Bt[row * 40 + c8] = w;
            }
        } else {
            const int d0 = (kk0 - 2) * 32;
            {
                int row = t >> 2, c8 = (t & 3) * 8;
                us8 w = *(const us8*)&qg[((size_t)b * S_ + s0 + row) * KD_ + h * DK_ + d0 + c8];
                *(us8*)&At[row * 40 + c8] = w;
            }
#pragma unroll
            for (int p = 0; p < 4; ++p) {
                int q = t + p * 256;
                int row = q >> 2, c8 = (q & 3) * 8;
                us8 w = *(const us8*)&St[(((size_t)bhc) * 512 + eh + row) * 256 + d0 + c8];
                *(us8*)&Bt[row * 40 + c8] = w;
            }
        }
        __syncthreads();

        bf16x8 af[4], bfr[4];
#pragma unroll
        for (int i = 0; i < 4; ++i)
            af[i] = *(const bf16x8*)&At[(i * 16 + l16) * 40 + quad * 8];
#pragma unroll
        for (int j = 0; j < 4; ++j)
            bfr[j] = *(const bf16x8*)&Bt[(we + j * 16 + l16) * 40 + quad * 8];
#pragma unroll
        for (int i = 0; i < 4; ++i)
#pragma unroll
            for (int j = 0; j < 4; ++j)
                acc[i][j] = __builtin_amdgcn_mfma_f32_16x16x32_bf16(af[i], bfr[j], acc[i][j], 0, 0, 0);
    }

#pragma unroll
    for (int i = 0; i < 4; ++i)
#pragma unroll
        for (int j = 0; j < 4; ++j)
#pragma unroll
            for (int r = 0; r < 4; ++r) {
                int m = i * 16 + quad * 4 + r;
                int e = eh + we + j * 16 + l16;
                o[((size_t)b * S_ + s0 + m) * VD_ + h * DV_ + e] = f2bf(acc[i][j][r]);
            }
}

// ---------------------------------------------------------------------------
// Post: RMS-norm over Dv=512 per (b,s,h) + gated swish; bf16 o in,
// g from fused qkvg cols (offset 4096, stride ND_), bf16 out.
// ---------------------------------------------------------------------------
__global__ __launch_bounds__(256) void postnorm(const unsigned short* __restrict__ o,
                                                const unsigned short* __restrict__ qkvg,
                                                const float* __restrict__ gnw,
                                                unsigned short* __restrict__ obf) {
    const int row = blockIdx.x;
    const int wave = threadIdx.x >> 6;
    const int lane = threadIdx.x & 63;
    const size_t base = (size_t)row * VD_ + wave * 512;
    const size_t gbase = (size_t)row * ND_ + 4096 + wave * 512;
    float x[8];
    float ss = 0.f;
#pragma unroll
    for (int j = 0; j < 8; ++j) {
        x[j] = bf2f(o[base + lane + j * 64]);
        ss += x[j] * x[j];
    }
#pragma unroll
    for (int off = 32; off; off >>= 1) ss += __shfl_xor(ss, off);
    const float inv = 1.0f / sqrtf(ss * (1.0f / 512.0f) + 1e-5f);
#pragma unroll
    for (int j = 0; j < 8; ++j) {
        int e = lane + j * 64;
        float gv = bf2f(qkvg[gbase + e]);
        float sig = 1.0f / (1.0f + expf(-gv));
        obf[base + e] = f2bf(x[j] * inv * gnw[e] * (gv * sig));
    }
}

// ---------------------------------------------------------------------------
extern "C" void kernel_launch(void* const* d_in, const int* in_sizes, int n_in,
                              void* d_out, int out_size, void* d_ws, size_t ws_size,
                              hipStream_t stream) {
    const float* x    = (const float*)d_in[0];
    const float* Wq   = (const float*)d_in[1];
    const float* Wk   = (const float*)d_in[2];
    const float* Wv   = (const float*)d_in[3];
    const float* Wgk1 = (const float*)d_in[4];
    const float* Wgk2 = (const float*)d_in[5];
    const float* bgk2 = (const float*)d_in[6];
    const float* Wg   = (const float*)d_in[7];
    const float* gnw  = (const float*)d_in[8];
    const float* Wo   = (const float*)d_in[9];
    float* out = (float*)d_out;

    float* ws = (float*)d_ws;
    const size_t MF = 1048576;
    typedef unsigned short us;
    // --- long-lived ---
    us* WotT   = (us*)(ws);                      // [2048][2048] bf16   0..2M
    us* qkvg   = (us*)(ws + 2 * MF);             // [4096][6144] bf16   2..15M (12.58M)
    us* qg     = (us*)(ws + 15 * MF);            // [4096][1024] bf16   15..17M
    us* kg     = (us*)(ws + 17 * MF);            // [4096][1024] bf16   17..19M
    us* kgT    = (us*)(ws + 19 * MF);            // [8*256][2048] bf16  19..21M
    us* vT     = (us*)(ws + 21 * MF);            // [8*512][2048] bf16  21..25M
    float* T   = ws + 25 * MF;                   // 65536
    float* gle = T + 65536;                      // 65536
    us* Asg    = (us*)(ws + 25 * MF + 131072);   // 1M shorts
    us* DtSt   = (us*)(ws + 25 * MF + 786432);   // 32M shorts: 25.75..41.75M
    // --- scratch (lifetime-shared) ---
    us* xb     = (us*)(ws + 41 * MF + 786432);   // x bf16 4M (dead after QKVG GEMM)
    us* WcatT  = (us*)(ws + 45 * MF + 786432);   // [6144][2048] bf16 6.29M (dead after QKVG GEMM)
    us* o      = (us*)(ws + 45 * MF + 786432);   // o bf16 4M (alias WcatT; written by pass_c2)
    us* obf    = (us*)(ws + 49 * MF + 786432);   // normed o bf16 2M: 49.75..51.75M

    dim3 blk(256);
    // gemm_n16 also emits xb = bf16(x) during staging (conv fused)
    gemm_n16<<<M_ / 16, blk, 0, stream>>>(x, Wgk1, T, xb);
    // all five weight transposes in one launch
    tr_w_all<<<dim3(256, 64), blk, 0, stream>>>(Wq, Wk, Wv, Wg, Wo, WcatT, WotT);

    // fused projection: qkvg = xb @ WcatT^T  (M=4096, N=6144, K=2048)
    gemm_bt<<<dim3(48, 32), blk, 0, stream>>>(xb, WcatT, nullptr, qkvg, M_, ND_, HD_);
    tr_v<<<dim3(64, 128), blk, 0, stream>>>(qkvg, vT);

    // gate_prep computes gk in-register (gk_act fused)
    gate_prep<<<256, dim3(1024), 0, stream>>>(qkvg, T, Wgk2, bgk2, qg, kg, kgT, gle);

    pass_c1<<<256, blk, 0, stream>>>(qg, kg, Asg);
    pass_ab<<<dim3(4, 16, 8), blk, 0, stream>>>(kgT, vT, gle, DtSt);
    pass_c2<<<dim3(2, 1, 256), blk, 0, stream>>>(qg, vT, Asg, DtSt, o);
    postnorm<<<M_, blk, 0, stream>>>(o, qkvg, gnw, obf);
    gemm_bt<<<dim3(16, 32), blk, 0, stream>>>(obf, WotT, out, nullptr, M_, HD_, VD_);
}